// Round 7
// baseline (359.248 us; speedup 1.0000x reference)
//
#include <hip/hip_runtime.h>
#include <hip/hip_bf16.h>

#define NN 50000
#define EE 800000
#define FD 128
#define NG 128
#define NC 10

typedef __attribute__((ext_vector_type(8))) short bf16x8;
typedef __attribute__((ext_vector_type(4))) float f32x4;

__device__ __forceinline__ float bf2f(unsigned short u) {
    return __uint_as_float(((unsigned int)u) << 16);
}
__device__ __forceinline__ unsigned short f2bf(float f) {
    unsigned int u = __float_as_uint(f);
    unsigned int r = (u >> 16) & 1u;
    u += 0x7fffu + r;
    return (unsigned short)(u >> 16);
}
__device__ __forceinline__ float ldf(const void* p, long i, int bf) {
    return bf ? bf2f(((const unsigned short*)p)[i]) : ((const float*)p)[i];
}

// ---------------- dtype detection ----------------
__global__ void detect_k(const unsigned short* xu, const unsigned int* eu, int* flags) {
    __shared__ int sbig, snz;
    if (threadIdx.x == 0) { sbig = 0; snz = 0; }
    __syncthreads();
    int t = threadIdx.x;
    float f = bf2f(xu[t * 2]);
    if (!(fabsf(f) < 1.0e6f)) atomicOr(&sbig, 1);
    if (eu[t * 2 + 1] != 0u) atomicOr(&snz, 1);
    __syncthreads();
    if (t == 0) {
        flags[0] = sbig ? 0 : 1;
        flags[1] = snz ? 0 : 1;
    }
}

// ---------------- params: W1..W3 -> transposed bf16 (Wt[n][k]); biases/lin -> f32 ----------------
__global__ void cvt_params_k(const int* flags,
                             const void* w1, const void* b1, const void* w2, const void* b2,
                             const void* w3, const void* b3, const void* lw, const void* lb,
                             unsigned short* wt, float* bfv, float* lwf, float* lbf) {
    int i = blockIdx.x * 256 + threadIdx.x;
    int bf = flags[0];
    if (i < 16384) {
        int k = i >> 7, n = i & 127;
        wt[n * 128 + k] = f2bf(ldf(w1, i, bf));
    } else if (i < 32768) {
        int j = i - 16384; int k = j >> 7, n = j & 127;
        wt[16384 + n * 128 + k] = f2bf(ldf(w2, j, bf));
    } else if (i < 49152) {
        int j = i - 32768; int k = j >> 7, n = j & 127;
        wt[32768 + n * 128 + k] = f2bf(ldf(w3, j, bf));
    }
    else if (i < 49280)  bfv[i - 49152] = ldf(b1, i - 49152, bf);
    else if (i < 49408)  bfv[i - 49152] = ldf(b2, i - 49280, bf);
    else if (i < 49536)  bfv[i - 49152] = ldf(b3, i - 49408, bf);
    else if (i < 50816)  lwf[i - 49536] = ldf(lw, i - 49536, bf);
    else if (i < 50826)  lbf[i - 50816] = ldf(lb, i - 50816, bf);
}

// ---------------- degree count, straight from edge_index dst half ----------------
__global__ void deg_k(const int* flags, const unsigned int* eu, int* deg) {
    int i = blockIdx.x * 256 + threadIdx.x;
    if (i < EE) {
        int d = (int)(flags[1] ? eu[2 * (long)EE + 2 * (long)i] : eu[EE + i]);
        d = ((unsigned)d < NN) ? d : 0;
        atomicAdd(&deg[d], 1);
    }
}

// ---------------- graph run boundaries (batch sorted): starts[g] = first node of graph g ----------------
__global__ void bounds_k(const int* flags, const unsigned int* bu, int* starts) {
    int n = blockIdx.x * 256 + threadIdx.x;
    if (n >= NN) return;
    int i64 = flags[1];
    int g = (int)(i64 ? bu[2 * (long)n] : bu[n]);
    g = ((unsigned)g < NG) ? g : 0;
    int gp = -1;
    if (n > 0) {
        gp = (int)(i64 ? bu[2 * (long)(n - 1)] : bu[n - 1]);
        gp = ((unsigned)gp < NG) ? gp : 0;
    }
    for (int gg = gp + 1; gg <= g; gg++) starts[gg] = n;
    if (n == NN - 1) {
        for (int gg = g + 1; gg <= NG; gg++) starts[gg] = NN;
    }
}

// ---------------- scan K1: per-block sums ----------------
__global__ __launch_bounds__(256) void bsum_k(const int* deg, int* bsum) {
    __shared__ int sd[256];
    int i = blockIdx.x * 256 + threadIdx.x;
    sd[threadIdx.x] = (i < NN) ? deg[i] : 0;
    __syncthreads();
    for (int s = 128; s > 0; s >>= 1) {
        if (threadIdx.x < s) sd[threadIdx.x] += sd[threadIdx.x + s];
        __syncthreads();
    }
    if (threadIdx.x == 0) bsum[blockIdx.x] = sd[0];
}

// ---------------- scan K2: single-block exclusive scan of block sums ----------------
__global__ __launch_bounds__(256) void bscan_k(const int* bsum, int* bofs, int nblk, int* rowptr) {
    __shared__ int sb[256];
    int t = threadIdx.x;
    sb[t] = (t < nblk) ? bsum[t] : 0;
    __syncthreads();
    if (t == 0) {
        int a = 0;
        for (int b = 0; b < nblk; b++) { int v = sb[b]; sb[b] = a; a += v; }
        rowptr[NN] = a; // == EE
    }
    __syncthreads();
    if (t < nblk) bofs[t] = sb[t];
}

// ---------------- scan K3: per-block Hillis-Steele + block offset, fused dinv ----------------
__global__ __launch_bounds__(256) void scan3_k(const int* deg, const int* bofs,
                                               int* rowptr, int* pos, float* dinv) {
    __shared__ int sd[256];
    int b = blockIdx.x, t = threadIdx.x;
    int i = b * 256 + t;
    int v = (i < NN) ? deg[i] : 0;
    sd[t] = v;
    __syncthreads();
    for (int off = 1; off < 256; off <<= 1) {
        int add = (t >= off) ? sd[t - off] : 0;
        __syncthreads();
        sd[t] += add;
        __syncthreads();
    }
    int excl = bofs[b] + sd[t] - v;
    if (i < NN) {
        rowptr[i] = excl; pos[i] = excl;
        dinv[i] = rsqrtf((float)(v + 1));
    }
}

// ---------------- CSR fill, straight from edge_index ----------------
__global__ void fill_k(const int* flags, const unsigned int* eu, int* pos, int* colsrc) {
    int e = blockIdx.x * 256 + threadIdx.x;
    if (e < EE) {
        int i64 = flags[1];
        int s = (int)(i64 ? eu[2 * (long)e] : eu[e]);
        int d = (int)(i64 ? eu[2 * (long)EE + 2 * (long)e] : eu[EE + e]);
        s = ((unsigned)s < NN) ? s : 0;
        d = ((unsigned)d < NN) ? d : 0;
        int idx = atomicAdd(&pos[d], 1);
        if ((unsigned)idx < EE) colsrc[idx] = s;
    }
}

// ---------------- MFMA GEMM: out[nrows x 128] bf16 = in[nrows x 128] @ W ----------------
__global__ __launch_bounds__(256) void gemm_mfma_k(const void* in, const int* flags, int raw,
                                                   const unsigned short* wtp,
                                                   unsigned short* outp, int nrows) {
    __shared__ unsigned short As[64][136];
    __shared__ unsigned short Ws[128][136];
    int tid = threadIdx.x;
    int row0 = blockIdx.x * 64;

    for (int it = tid; it < 2048; it += 256) {
        int n = it >> 4, seg = it & 15;
        *(uint4*)&Ws[n][seg * 8] = ((const uint4*)wtp)[it];
    }
    int isbf = raw ? flags[0] : 1;  // wave-uniform
    if (isbf) {
        const unsigned short* inb = (const unsigned short*)in;
        for (int it = tid; it < 1024; it += 256) {
            int r = it >> 4, seg = it & 15;
            int gr = row0 + r;
            uint4 v = make_uint4(0u, 0u, 0u, 0u);
            if (gr < nrows) v = ((const uint4*)inb)[(size_t)gr * 16 + seg];
            *(uint4*)&As[r][seg * 8] = v;
        }
    } else {
        const float* inf = (const float*)in;
        for (int it = tid; it < 1024; it += 256) {
            int r = it >> 4, seg = it & 15;
            int gr = row0 + r;
            unsigned short tmp[8];
            if (gr < nrows) {
#pragma unroll
                for (int q = 0; q < 8; q++) tmp[q] = f2bf(inf[(size_t)gr * 128 + seg * 8 + q]);
            } else {
#pragma unroll
                for (int q = 0; q < 8; q++) tmp[q] = 0;
            }
#pragma unroll
            for (int q = 0; q < 8; q++) As[r][seg * 8 + q] = tmp[q];
        }
    }
    __syncthreads();

    int wv = tid >> 6, lane = tid & 63;
    int m = lane & 15, quad = lane >> 4;
    int arow = wv * 16 + m;

    bf16x8 af[4];
#pragma unroll
    for (int ks = 0; ks < 4; ks++)
        af[ks] = *(const bf16x8*)&As[arow][ks * 32 + quad * 8];

    int grbase = row0 + wv * 16;
#pragma unroll
    for (int tile = 0; tile < 8; tile++) {
        f32x4 acc = {0.f, 0.f, 0.f, 0.f};
        int n = tile * 16 + m;
#pragma unroll
        for (int ks = 0; ks < 4; ks++) {
            bf16x8 bfr = *(const bf16x8*)&Ws[n][ks * 32 + quad * 8];
            acc = __builtin_amdgcn_mfma_f32_16x16x32_bf16(af[ks], bfr, acc, 0, 0, 0);
        }
#pragma unroll
        for (int r = 0; r < 4; r++) {
            int orow = grbase + quad * 4 + r;
            if (orow < nrows) outp[(size_t)orow * 128 + n] = f2bf(acc[r]);
        }
    }
}

// ---------------- aggregation: one wave per node; lane-parallel edge metadata + shfl broadcast ----------------
__global__ __launch_bounds__(256) void agg_k(const unsigned short* t, unsigned short* outp,
                                             const float* bias, const int* rowptr, const int* colsrc,
                                             const float* dinv, int relu) {
    int gtid = blockIdx.x * 256 + threadIdx.x;
    int n = gtid >> 6;
    int lane = threadIdx.x & 63;
    if (n >= NN) return;
    float dn = dinv[n];
    float ax = bias[2 * lane], ay = bias[2 * lane + 1];
    unsigned int sf = ((const unsigned int*)(t + (size_t)n * 128))[lane];
    float dn2 = dn * dn;
    ax += dn2 * bf2f((unsigned short)(sf & 0xffffu));
    ay += dn2 * bf2f((unsigned short)(sf >> 16));

    int j0 = rowptr[n];
    int cnt = rowptr[n + 1] - j0;
    for (int e0 = 0; e0 < cnt; e0 += 64) {
        int m = cnt - e0; if (m > 64) m = 64;
        int idx = 0;
        if (lane < m) {
            idx = colsrc[j0 + e0 + lane];
            idx = ((unsigned)idx < NN) ? idx : 0;
        }
        float dv = dinv[idx];
        int e = 0;
        for (; e + 3 < m; e += 4) {
            int s0 = __shfl(idx, e),     s1 = __shfl(idx, e + 1);
            int s2 = __shfl(idx, e + 2), s3 = __shfl(idx, e + 3);
            float w0 = dn * __shfl(dv, e),     w1 = dn * __shfl(dv, e + 1);
            float w2 = dn * __shfl(dv, e + 2), w3 = dn * __shfl(dv, e + 3);
            unsigned int v0 = ((const unsigned int*)(t + (size_t)s0 * 128))[lane];
            unsigned int v1 = ((const unsigned int*)(t + (size_t)s1 * 128))[lane];
            unsigned int v2 = ((const unsigned int*)(t + (size_t)s2 * 128))[lane];
            unsigned int v3 = ((const unsigned int*)(t + (size_t)s3 * 128))[lane];
            ax += w0 * bf2f((unsigned short)(v0 & 0xffffu)) + w1 * bf2f((unsigned short)(v1 & 0xffffu))
                + w2 * bf2f((unsigned short)(v2 & 0xffffu)) + w3 * bf2f((unsigned short)(v3 & 0xffffu));
            ay += w0 * bf2f((unsigned short)(v0 >> 16)) + w1 * bf2f((unsigned short)(v1 >> 16))
                + w2 * bf2f((unsigned short)(v2 >> 16)) + w3 * bf2f((unsigned short)(v3 >> 16));
        }
        for (; e < m; e++) {
            int s = __shfl(idx, e);
            float w = dn * __shfl(dv, e);
            unsigned int v = ((const unsigned int*)(t + (size_t)s * 128))[lane];
            ax += w * bf2f((unsigned short)(v & 0xffffu));
            ay += w * bf2f((unsigned short)(v >> 16));
        }
    }
    if (relu) { ax = fmaxf(ax, 0.f); ay = fmaxf(ay, 0.f); }
    unsigned int o = (unsigned int)f2bf(ax) | ((unsigned int)f2bf(ay) << 16);
    ((unsigned int*)(outp + (size_t)n * 128))[lane] = o;
}

// ---------------- pooling (bf16 h): 32 nodes/block, run-based + boundary atomics ----------------
#define POOL_NPB 32
__global__ __launch_bounds__(128) void pool_k(const unsigned short* h, const int* flags,
                                              const unsigned int* bu, float* sums) {
    int t = threadIdx.x;
    int n0 = blockIdx.x * POOL_NPB;
    if (n0 >= NN) return;
    int n1 = n0 + POOL_NPB; if (n1 > NN) n1 = NN;
    int i64 = flags[1];
    auto bid = [&](int n) {
        int g = (int)(i64 ? bu[2 * (long)n] : bu[n]);
        return ((unsigned)g < NG) ? g : 0;
    };
    int cur = bid(n0);
    float acc = 0.f;
    for (int n = n0; n < n1; n++) {
        int g = bid(n);
        if (g != cur) {
            atomicAdd(&sums[(size_t)cur * 128 + t], acc);
            acc = 0.f; cur = g;
        }
        acc += bf2f(h[(size_t)n * 128 + t]);
    }
    atomicAdd(&sums[(size_t)cur * 128 + t], acc);
}

// ---------------- head ----------------
__global__ __launch_bounds__(128) void final_k(const float* sums, const int* starts,
                                               const float* lwf, const float* lbf,
                                               void* outp, const int* flags) {
    __shared__ float p[128];
    int g = blockIdx.x, t = threadIdx.x;
    int c = starts[g + 1] - starts[g]; if (c < 1) c = 1;
    p[t] = sums[(size_t)g * 128 + t] / (float)c;
    __syncthreads();
    if (t < NC) {
        float acc = lbf[t];
#pragma unroll 16
        for (int f = 0; f < 128; f++) acc += p[f] * lwf[f * NC + t];
        if (flags[0]) ((unsigned short*)outp)[g * NC + t] = f2bf(acc);
        else          ((float*)outp)[g * NC + t] = acc;
    }
}

extern "C" void kernel_launch(void* const* d_in, const int* in_sizes, int n_in,
                              void* d_out, int out_size, void* d_ws, size_t ws_size,
                              hipStream_t stream) {
    char* ws = (char*)d_ws;
    size_t off = 0;
    auto alloc = [&](size_t bytes) { size_t o = off; off = (off + bytes + 255) & ~(size_t)255; return o; };

    int*   flags  = (int*)(ws + alloc(32 * 4));
    int*   deg    = (int*)(ws + alloc((size_t)NN * 4));
    int*   rowptr = (int*)(ws + alloc((size_t)(NN + 1) * 4));
    int*   pos    = (int*)(ws + alloc((size_t)NN * 4));
    int*   bsum   = (int*)(ws + alloc((size_t)256 * 4));
    int*   bofs   = (int*)(ws + alloc((size_t)256 * 4));
    int*   starts = (int*)(ws + alloc((size_t)(NG + 1) * 4));
    int*   colsrc = (int*)(ws + alloc((size_t)EE * 4));
    float* dinv   = (float*)(ws + alloc((size_t)NN * 4));
    unsigned short* wt  = (unsigned short*)(ws + alloc((size_t)3 * 16384 * 2));
    float* bfv    = (float*)(ws + alloc((size_t)3 * 128 * 4));
    float* lwf    = (float*)(ws + alloc((size_t)1280 * 4));
    float* lbf    = (float*)(ws + alloc((size_t)16 * 4));
    float* sums   = (float*)(ws + alloc((size_t)NG * 128 * 4));
    unsigned short* tbuf = (unsigned short*)(ws + alloc((size_t)NN * 128 * 2));
    unsigned short* hbuf = (unsigned short*)(ws + alloc((size_t)NN * 128 * 2));

    const void* x = d_in[0];
    const unsigned int* eu = (const unsigned int*)d_in[1];
    const unsigned int* bu = (const unsigned int*)d_in[2];

    hipMemsetAsync(deg, 0, (size_t)NN * 4, stream);
    hipMemsetAsync(sums, 0, (size_t)NG * 128 * 4, stream);

    detect_k<<<1, 256, 0, stream>>>((const unsigned short*)x, eu, flags);
    cvt_params_k<<<199, 256, 0, stream>>>(flags, d_in[3], d_in[4], d_in[5], d_in[6],
                                          d_in[7], d_in[8], d_in[9], d_in[10],
                                          wt, bfv, lwf, lbf);
    deg_k<<<(EE + 255) / 256, 256, 0, stream>>>(flags, eu, deg);
    bounds_k<<<(NN + 255) / 256, 256, 0, stream>>>(flags, bu, starts);

    int nblk = (NN + 255) / 256; // 196
    bsum_k<<<nblk, 256, 0, stream>>>(deg, bsum);
    bscan_k<<<1, 256, 0, stream>>>(bsum, bofs, nblk, rowptr);
    scan3_k<<<nblk, 256, 0, stream>>>(deg, bofs, rowptr, pos, dinv);
    fill_k<<<(EE + 255) / 256, 256, 0, stream>>>(flags, eu, pos, colsrc);

    int gemm_blocks = (NN + 63) / 64;
    int agg_blocks = (NN * 64 + 255) / 256;

    gemm_mfma_k<<<gemm_blocks, 256, 0, stream>>>(x, flags, 1, wt, tbuf, NN);
    agg_k<<<agg_blocks, 256, 0, stream>>>(tbuf, hbuf, bfv, rowptr, colsrc, dinv, 1);
    gemm_mfma_k<<<gemm_blocks, 256, 0, stream>>>(hbuf, flags, 0, wt + 16384, tbuf, NN);
    agg_k<<<agg_blocks, 256, 0, stream>>>(tbuf, hbuf, bfv + 128, rowptr, colsrc, dinv, 1);
    gemm_mfma_k<<<gemm_blocks, 256, 0, stream>>>(hbuf, flags, 0, wt + 32768, tbuf, NN);
    agg_k<<<agg_blocks, 256, 0, stream>>>(tbuf, hbuf, bfv + 256, rowptr, colsrc, dinv, 0);

    pool_k<<<(NN + POOL_NPB - 1) / POOL_NPB, 128, 0, stream>>>(hbuf, flags, bu, sums);
    final_k<<<NG, 128, 0, stream>>>(sums, starts, lwf, lbf, d_out, flags);
}

// Round 8
// 339.964 us; speedup vs baseline: 1.0567x; 1.0567x over previous
//
#include <hip/hip_runtime.h>
#include <hip/hip_bf16.h>

#define NN 50000
#define EE 800000
#define FD 128
#define NG 128
#define NC 10

typedef __attribute__((ext_vector_type(8))) short bf16x8;
typedef __attribute__((ext_vector_type(4))) float f32x4;

__device__ __forceinline__ float bf2f(unsigned short u) {
    return __uint_as_float(((unsigned int)u) << 16);
}
__device__ __forceinline__ unsigned short f2bf(float f) {
    unsigned int u = __float_as_uint(f);
    unsigned int r = (u >> 16) & 1u;
    u += 0x7fffu + r;
    return (unsigned short)(u >> 16);
}
__device__ __forceinline__ float ldf(const void* p, long i, int bf) {
    return bf ? bf2f(((const unsigned short*)p)[i]) : ((const float*)p)[i];
}

// ---------------- dtype detection ----------------
__global__ void detect_k(const unsigned short* xu, const unsigned int* eu, int* flags) {
    __shared__ int sbig, snz;
    if (threadIdx.x == 0) { sbig = 0; snz = 0; }
    __syncthreads();
    int t = threadIdx.x;
    float f = bf2f(xu[t * 2]);
    if (!(fabsf(f) < 1.0e6f)) atomicOr(&sbig, 1);
    if (eu[t * 2 + 1] != 0u) atomicOr(&snz, 1);
    __syncthreads();
    if (t == 0) {
        flags[0] = sbig ? 0 : 1;
        flags[1] = snz ? 0 : 1;
    }
}

// ---------------- params: W1..W3 -> transposed bf16 (Wt[n][k]); biases/lin -> f32 ----------------
__global__ void cvt_params_k(const int* flags,
                             const void* w1, const void* b1, const void* w2, const void* b2,
                             const void* w3, const void* b3, const void* lw, const void* lb,
                             unsigned short* wt, float* bfv, float* lwf, float* lbf) {
    int i = blockIdx.x * 256 + threadIdx.x;
    int bf = flags[0];
    if (i < 16384) {
        int k = i >> 7, n = i & 127;
        wt[n * 128 + k] = f2bf(ldf(w1, i, bf));
    } else if (i < 32768) {
        int j = i - 16384; int k = j >> 7, n = j & 127;
        wt[16384 + n * 128 + k] = f2bf(ldf(w2, j, bf));
    } else if (i < 49152) {
        int j = i - 32768; int k = j >> 7, n = j & 127;
        wt[32768 + n * 128 + k] = f2bf(ldf(w3, j, bf));
    }
    else if (i < 49280)  bfv[i - 49152] = ldf(b1, i - 49152, bf);
    else if (i < 49408)  bfv[i - 49152] = ldf(b2, i - 49280, bf);
    else if (i < 49536)  bfv[i - 49152] = ldf(b3, i - 49408, bf);
    else if (i < 50816)  lwf[i - 49536] = ldf(lw, i - 49536, bf);
    else if (i < 50826)  lbf[i - 50816] = ldf(lb, i - 50816, bf);
}

// ---------------- degree count, straight from edge_index dst half ----------------
__global__ void deg_k(const int* flags, const unsigned int* eu, int* deg) {
    int i = blockIdx.x * 256 + threadIdx.x;
    if (i >= EE) return;
    int d;
    if (flags[1]) d = (int)((const uint2*)eu)[(long)EE + i].x;  // coalesced 8B
    else          d = (int)eu[EE + i];
    d = ((unsigned)d < NN) ? d : 0;
    atomicAdd(&deg[d], 1);
}

// ---------------- graph run boundaries (batch sorted): starts[g] = first node of graph g ----------------
__global__ void bounds_k(const int* flags, const unsigned int* bu, int* starts) {
    int n = blockIdx.x * 256 + threadIdx.x;
    if (n >= NN) return;
    int i64 = flags[1];
    int g = (int)(i64 ? bu[2 * (long)n] : bu[n]);
    g = ((unsigned)g < NG) ? g : 0;
    int gp = -1;
    if (n > 0) {
        gp = (int)(i64 ? bu[2 * (long)(n - 1)] : bu[n - 1]);
        gp = ((unsigned)gp < NG) ? gp : 0;
    }
    for (int gg = gp + 1; gg <= g; gg++) starts[gg] = n;
    if (n == NN - 1) {
        for (int gg = g + 1; gg <= NG; gg++) starts[gg] = NN;
    }
}

// ---------------- scan K1: per-block sums ----------------
__global__ __launch_bounds__(256) void bsum_k(const int* deg, int* bsum) {
    __shared__ int sd[256];
    int i = blockIdx.x * 256 + threadIdx.x;
    sd[threadIdx.x] = (i < NN) ? deg[i] : 0;
    __syncthreads();
    for (int s = 128; s > 0; s >>= 1) {
        if (threadIdx.x < s) sd[threadIdx.x] += sd[threadIdx.x + s];
        __syncthreads();
    }
    if (threadIdx.x == 0) bsum[blockIdx.x] = sd[0];
}

// ---------------- scan K2: single-block exclusive scan of block sums ----------------
__global__ __launch_bounds__(256) void bscan_k(const int* bsum, int* bofs, int nblk, int* rowptr) {
    __shared__ int sb[256];
    int t = threadIdx.x;
    sb[t] = (t < nblk) ? bsum[t] : 0;
    __syncthreads();
    if (t == 0) {
        int a = 0;
        for (int b = 0; b < nblk; b++) { int v = sb[b]; sb[b] = a; a += v; }
        rowptr[NN] = a; // == EE
    }
    __syncthreads();
    if (t < nblk) bofs[t] = sb[t];
}

// ---------------- scan K3: per-block Hillis-Steele + block offset, fused dinv ----------------
__global__ __launch_bounds__(256) void scan3_k(const int* deg, const int* bofs,
                                               int* rowptr, int* pos, float* dinv) {
    __shared__ int sd[256];
    int b = blockIdx.x, t = threadIdx.x;
    int i = b * 256 + t;
    int v = (i < NN) ? deg[i] : 0;
    sd[t] = v;
    __syncthreads();
    for (int off = 1; off < 256; off <<= 1) {
        int add = (t >= off) ? sd[t - off] : 0;
        __syncthreads();
        sd[t] += add;
        __syncthreads();
    }
    int excl = bofs[b] + sd[t] - v;
    if (i < NN) {
        rowptr[i] = excl; pos[i] = excl;
        dinv[i] = rsqrtf((float)(v + 1));
    }
}

// ---------------- CSR fill (uint16 colsrc), straight from edge_index ----------------
__global__ void fill_k(const int* flags, const unsigned int* eu, int* pos, unsigned short* colsrc) {
    int e = blockIdx.x * 256 + threadIdx.x;
    if (e >= EE) return;
    int s, d;
    if (flags[1]) {
        s = (int)((const uint2*)eu)[e].x;
        d = (int)((const uint2*)eu)[(long)EE + e].x;
    } else {
        s = (int)eu[e];
        d = (int)eu[EE + e];
    }
    s = ((unsigned)s < NN) ? s : 0;
    d = ((unsigned)d < NN) ? d : 0;
    int idx = atomicAdd(&pos[d], 1);
    if ((unsigned)idx < EE) colsrc[idx] = (unsigned short)s;
}

// ---------------- MFMA GEMM: out[nrows x 128] bf16 = in[nrows x 128] @ W ----------------
__global__ __launch_bounds__(256) void gemm_mfma_k(const void* in, const int* flags, int raw,
                                                   const unsigned short* wtp,
                                                   unsigned short* outp, int nrows) {
    __shared__ unsigned short As[64][136];
    __shared__ unsigned short Ws[128][136];
    int tid = threadIdx.x;
    int row0 = blockIdx.x * 64;

    for (int it = tid; it < 2048; it += 256) {
        int n = it >> 4, seg = it & 15;
        *(uint4*)&Ws[n][seg * 8] = ((const uint4*)wtp)[it];
    }
    int isbf = raw ? flags[0] : 1;  // wave-uniform
    if (isbf) {
        const unsigned short* inb = (const unsigned short*)in;
        for (int it = tid; it < 1024; it += 256) {
            int r = it >> 4, seg = it & 15;
            int gr = row0 + r;
            uint4 v = make_uint4(0u, 0u, 0u, 0u);
            if (gr < nrows) v = ((const uint4*)inb)[(size_t)gr * 16 + seg];
            *(uint4*)&As[r][seg * 8] = v;
        }
    } else {
        const float* inf = (const float*)in;
        for (int it = tid; it < 1024; it += 256) {
            int r = it >> 4, seg = it & 15;
            int gr = row0 + r;
            unsigned short tmp[8];
            if (gr < nrows) {
#pragma unroll
                for (int q = 0; q < 8; q++) tmp[q] = f2bf(inf[(size_t)gr * 128 + seg * 8 + q]);
            } else {
#pragma unroll
                for (int q = 0; q < 8; q++) tmp[q] = 0;
            }
#pragma unroll
            for (int q = 0; q < 8; q++) As[r][seg * 8 + q] = tmp[q];
        }
    }
    __syncthreads();

    int wv = tid >> 6, lane = tid & 63;
    int m = lane & 15, quad = lane >> 4;
    int arow = wv * 16 + m;

    bf16x8 af[4];
#pragma unroll
    for (int ks = 0; ks < 4; ks++)
        af[ks] = *(const bf16x8*)&As[arow][ks * 32 + quad * 8];

    int grbase = row0 + wv * 16;
#pragma unroll
    for (int tile = 0; tile < 8; tile++) {
        f32x4 acc = {0.f, 0.f, 0.f, 0.f};
        int n = tile * 16 + m;
#pragma unroll
        for (int ks = 0; ks < 4; ks++) {
            bf16x8 bfr = *(const bf16x8*)&Ws[n][ks * 32 + quad * 8];
            acc = __builtin_amdgcn_mfma_f32_16x16x32_bf16(af[ks], bfr, acc, 0, 0, 0);
        }
#pragma unroll
        for (int r = 0; r < 4; r++) {
            int orow = grbase + quad * 4 + r;
            if (orow < nrows) outp[(size_t)orow * 128 + n] = f2bf(acc[r]);
        }
    }
}

// ---------------- aggregation: one wave per node; lane-parallel edge metadata + shfl broadcast ----------------
__global__ __launch_bounds__(256) void agg_k(const unsigned short* t, unsigned short* outp,
                                             const float* bias, const int* rowptr,
                                             const unsigned short* colsrc,
                                             const float* dinv, int relu) {
    int gtid = blockIdx.x * 256 + threadIdx.x;
    int n = gtid >> 6;
    int lane = threadIdx.x & 63;
    if (n >= NN) return;
    float dn = dinv[n];
    float ax = bias[2 * lane], ay = bias[2 * lane + 1];
    unsigned int sf = ((const unsigned int*)(t + (size_t)n * 128))[lane];
    float dn2 = dn * dn;
    ax += dn2 * bf2f((unsigned short)(sf & 0xffffu));
    ay += dn2 * bf2f((unsigned short)(sf >> 16));

    int j0 = rowptr[n];
    int cnt = rowptr[n + 1] - j0;
    for (int e0 = 0; e0 < cnt; e0 += 64) {
        int m = cnt - e0; if (m > 64) m = 64;
        int idx = 0;
        if (lane < m) {
            idx = (int)colsrc[j0 + e0 + lane];
            idx = ((unsigned)idx < NN) ? idx : 0;
        }
        float dv = dinv[idx];
        int e = 0;
        for (; e + 7 < m; e += 8) {
            int s0 = __shfl(idx, e),     s1 = __shfl(idx, e + 1);
            int s2 = __shfl(idx, e + 2), s3 = __shfl(idx, e + 3);
            int s4 = __shfl(idx, e + 4), s5 = __shfl(idx, e + 5);
            int s6 = __shfl(idx, e + 6), s7 = __shfl(idx, e + 7);
            float w0 = dn * __shfl(dv, e),     w1 = dn * __shfl(dv, e + 1);
            float w2 = dn * __shfl(dv, e + 2), w3 = dn * __shfl(dv, e + 3);
            float w4 = dn * __shfl(dv, e + 4), w5 = dn * __shfl(dv, e + 5);
            float w6 = dn * __shfl(dv, e + 6), w7 = dn * __shfl(dv, e + 7);
            unsigned int v0 = ((const unsigned int*)(t + (size_t)s0 * 128))[lane];
            unsigned int v1 = ((const unsigned int*)(t + (size_t)s1 * 128))[lane];
            unsigned int v2 = ((const unsigned int*)(t + (size_t)s2 * 128))[lane];
            unsigned int v3 = ((const unsigned int*)(t + (size_t)s3 * 128))[lane];
            unsigned int v4 = ((const unsigned int*)(t + (size_t)s4 * 128))[lane];
            unsigned int v5 = ((const unsigned int*)(t + (size_t)s5 * 128))[lane];
            unsigned int v6 = ((const unsigned int*)(t + (size_t)s6 * 128))[lane];
            unsigned int v7 = ((const unsigned int*)(t + (size_t)s7 * 128))[lane];
            ax += w0 * bf2f((unsigned short)(v0 & 0xffffu)) + w1 * bf2f((unsigned short)(v1 & 0xffffu))
                + w2 * bf2f((unsigned short)(v2 & 0xffffu)) + w3 * bf2f((unsigned short)(v3 & 0xffffu))
                + w4 * bf2f((unsigned short)(v4 & 0xffffu)) + w5 * bf2f((unsigned short)(v5 & 0xffffu))
                + w6 * bf2f((unsigned short)(v6 & 0xffffu)) + w7 * bf2f((unsigned short)(v7 & 0xffffu));
            ay += w0 * bf2f((unsigned short)(v0 >> 16)) + w1 * bf2f((unsigned short)(v1 >> 16))
                + w2 * bf2f((unsigned short)(v2 >> 16)) + w3 * bf2f((unsigned short)(v3 >> 16))
                + w4 * bf2f((unsigned short)(v4 >> 16)) + w5 * bf2f((unsigned short)(v5 >> 16))
                + w6 * bf2f((unsigned short)(v6 >> 16)) + w7 * bf2f((unsigned short)(v7 >> 16));
        }
        for (; e + 3 < m; e += 4) {
            int s0 = __shfl(idx, e),     s1 = __shfl(idx, e + 1);
            int s2 = __shfl(idx, e + 2), s3 = __shfl(idx, e + 3);
            float w0 = dn * __shfl(dv, e),     w1 = dn * __shfl(dv, e + 1);
            float w2 = dn * __shfl(dv, e + 2), w3 = dn * __shfl(dv, e + 3);
            unsigned int v0 = ((const unsigned int*)(t + (size_t)s0 * 128))[lane];
            unsigned int v1 = ((const unsigned int*)(t + (size_t)s1 * 128))[lane];
            unsigned int v2 = ((const unsigned int*)(t + (size_t)s2 * 128))[lane];
            unsigned int v3 = ((const unsigned int*)(t + (size_t)s3 * 128))[lane];
            ax += w0 * bf2f((unsigned short)(v0 & 0xffffu)) + w1 * bf2f((unsigned short)(v1 & 0xffffu))
                + w2 * bf2f((unsigned short)(v2 & 0xffffu)) + w3 * bf2f((unsigned short)(v3 & 0xffffu));
            ay += w0 * bf2f((unsigned short)(v0 >> 16)) + w1 * bf2f((unsigned short)(v1 >> 16))
                + w2 * bf2f((unsigned short)(v2 >> 16)) + w3 * bf2f((unsigned short)(v3 >> 16));
        }
        for (; e < m; e++) {
            int s = __shfl(idx, e);
            float w = dn * __shfl(dv, e);
            unsigned int v = ((const unsigned int*)(t + (size_t)s * 128))[lane];
            ax += w * bf2f((unsigned short)(v & 0xffffu));
            ay += w * bf2f((unsigned short)(v >> 16));
        }
    }
    if (relu) { ax = fmaxf(ax, 0.f); ay = fmaxf(ay, 0.f); }
    unsigned int o = (unsigned int)f2bf(ax) | ((unsigned int)f2bf(ay) << 16);
    ((unsigned int*)(outp + (size_t)n * 128))[lane] = o;
}

// ---------------- fused pool + head: one block per graph ----------------
__global__ __launch_bounds__(128) void poolhead_k(const unsigned short* h, const int* starts,
                                                  const float* lwf, const float* lbf,
                                                  void* outp, const int* flags) {
    __shared__ float p[128];
    int g = blockIdx.x, t = threadIdx.x;
    int n0 = starts[g], n1 = starts[g + 1];
    float a0 = 0.f, a1 = 0.f, a2 = 0.f, a3 = 0.f;
    int n = n0;
    for (; n + 3 < n1; n += 4) {
        a0 += bf2f(h[(size_t)n * 128 + t]);
        a1 += bf2f(h[(size_t)(n + 1) * 128 + t]);
        a2 += bf2f(h[(size_t)(n + 2) * 128 + t]);
        a3 += bf2f(h[(size_t)(n + 3) * 128 + t]);
    }
    for (; n < n1; n++) a0 += bf2f(h[(size_t)n * 128 + t]);
    float acc = (a0 + a1) + (a2 + a3);
    int c = n1 - n0; if (c < 1) c = 1;
    p[t] = acc / (float)c;
    __syncthreads();
    if (t < NC) {
        float o = lbf[t];
#pragma unroll 16
        for (int f = 0; f < 128; f++) o += p[f] * lwf[f * NC + t];
        if (flags[0]) ((unsigned short*)outp)[g * NC + t] = f2bf(o);
        else          ((float*)outp)[g * NC + t] = o;
    }
}

extern "C" void kernel_launch(void* const* d_in, const int* in_sizes, int n_in,
                              void* d_out, int out_size, void* d_ws, size_t ws_size,
                              hipStream_t stream) {
    char* ws = (char*)d_ws;
    size_t off = 0;
    auto alloc = [&](size_t bytes) { size_t o = off; off = (off + bytes + 255) & ~(size_t)255; return o; };

    int*   flags  = (int*)(ws + alloc(32 * 4));
    int*   deg    = (int*)(ws + alloc((size_t)NN * 4));
    int*   rowptr = (int*)(ws + alloc((size_t)(NN + 1) * 4));
    int*   pos    = (int*)(ws + alloc((size_t)NN * 4));
    int*   bsum   = (int*)(ws + alloc((size_t)256 * 4));
    int*   bofs   = (int*)(ws + alloc((size_t)256 * 4));
    int*   starts = (int*)(ws + alloc((size_t)(NG + 1) * 4));
    unsigned short* colsrc = (unsigned short*)(ws + alloc((size_t)EE * 2));
    float* dinv   = (float*)(ws + alloc((size_t)NN * 4));
    unsigned short* wt  = (unsigned short*)(ws + alloc((size_t)3 * 16384 * 2));
    float* bfv    = (float*)(ws + alloc((size_t)3 * 128 * 4));
    float* lwf    = (float*)(ws + alloc((size_t)1280 * 4));
    float* lbf    = (float*)(ws + alloc((size_t)16 * 4));
    unsigned short* tbuf = (unsigned short*)(ws + alloc((size_t)NN * 128 * 2));
    unsigned short* hbuf = (unsigned short*)(ws + alloc((size_t)NN * 128 * 2));

    const void* x = d_in[0];
    const unsigned int* eu = (const unsigned int*)d_in[1];
    const unsigned int* bu = (const unsigned int*)d_in[2];

    hipMemsetAsync(deg, 0, (size_t)NN * 4, stream);

    detect_k<<<1, 256, 0, stream>>>((const unsigned short*)x, eu, flags);
    cvt_params_k<<<199, 256, 0, stream>>>(flags, d_in[3], d_in[4], d_in[5], d_in[6],
                                          d_in[7], d_in[8], d_in[9], d_in[10],
                                          wt, bfv, lwf, lbf);
    deg_k<<<(EE + 255) / 256, 256, 0, stream>>>(flags, eu, deg);
    bounds_k<<<(NN + 255) / 256, 256, 0, stream>>>(flags, bu, starts);

    int nblk = (NN + 255) / 256; // 196
    bsum_k<<<nblk, 256, 0, stream>>>(deg, bsum);
    bscan_k<<<1, 256, 0, stream>>>(bsum, bofs, nblk, rowptr);
    scan3_k<<<nblk, 256, 0, stream>>>(deg, bofs, rowptr, pos, dinv);
    fill_k<<<(EE + 255) / 256, 256, 0, stream>>>(flags, eu, pos, colsrc);

    int gemm_blocks = (NN + 63) / 64;
    int agg_blocks = (NN * 64 + 255) / 256;

    gemm_mfma_k<<<gemm_blocks, 256, 0, stream>>>(x, flags, 1, wt, tbuf, NN);
    agg_k<<<agg_blocks, 256, 0, stream>>>(tbuf, hbuf, bfv, rowptr, colsrc, dinv, 1);
    gemm_mfma_k<<<gemm_blocks, 256, 0, stream>>>(hbuf, flags, 0, wt + 16384, tbuf, NN);
    agg_k<<<agg_blocks, 256, 0, stream>>>(tbuf, hbuf, bfv + 128, rowptr, colsrc, dinv, 1);
    gemm_mfma_k<<<gemm_blocks, 256, 0, stream>>>(hbuf, flags, 0, wt + 32768, tbuf, NN);
    agg_k<<<agg_blocks, 256, 0, stream>>>(tbuf, hbuf, bfv + 256, rowptr, colsrc, dinv, 0);

    poolhead_k<<<NG, 128, 0, stream>>>(hbuf, starts, lwf, lbf, d_out, flags);
}